// Round 5
// baseline (1205.614 us; speedup 1.0000x reference)
//
#include <hip/hip_runtime.h>

// RFNetwork recurrence (in_in_p is dead code; P = out_in_p):
//   out_t = (W + P) @ x_t ;  P = colrenorm(rowrenorm(P + l*outer(out,x)))
// One-step-lazy column factor f_j (<=1, no accumulation):
//   pass1 (wave=row): out_i = (W x)_i + sum_j Pt_ij f_j x_j ; R_i = sum_j Pt_ij f_j
//                     r_i from R1_i = R_i + l*out_i*sx   (sx precomputed per t)
//   pass2 (thread=4cols x 4rows, float4): v = r_i*(Pt f + l*out_i*x)
// Column-sum exchange = FIXED-POINT INTEGER ATOMIC ACCUMULATION at the LLC:
//   each block adds round(partial * 2^21) (exact f64 mul, i64) into
//   Sacc[t&1][j] via agent-scope atomic_add (u64). Integer adds commute
//   exactly -> bit-deterministic under any arrival order. Accumulators are
//   MONOTONE (never zeroed mid-run; no zeroing race under block skew); each
//   block keeps prev[parity][4] registers and decodes this step's sum as an
//   exact integer difference. Post-barrier read volume: 8 KB/block (vs 256 KB).
// Flag barrier: block b stores flags[b]=t+1 (agent atomic), wave0 polls all
// 64 flags with one 64-lane load until __all >= t+1. vmcnt drained by the
// preceding __syncthreads -> adds are at the LLC before the flag is visible.

typedef float f32x4 __attribute__((ext_vector_type(4)));

#define T_STEPS 128
#define N 1024
#define N4 256         // N/4
#define NB 64          // blocks
#define RPB 16         // rows per block
#define NT 1024        // threads per block (16 waves)
#define LMBDA 0.01f
#define SCALE_D 2097152.0           // 2^21 fixed-point scale
#define INV_SCALE_D (1.0 / 2097152.0)

__device__ __forceinline__ float wred(float v) {
#pragma unroll
  for (int off = 32; off; off >>= 1) v += __shfl_xor(v, off, 64);
  return v;  // all lanes hold the sum
}

__global__ __launch_bounds__(NT) void rf_step_kernel(
    const float* __restrict__ X,               // [T][N]
    const float* __restrict__ W,               // [N][N]
    float* __restrict__ OUT,                   // [T][N]
    unsigned long long* __restrict__ Sacc,     // [2][N] fixed-point colsum acc
    unsigned* __restrict__ flags) {            // [NB] monotone arrival flags
  __shared__ f32x4 P4[RPB][N4];   // 64 KB P_tilde
  __shared__ f32x4 F4[N4];        // 4 KB  column factor f
  __shared__ f32x4 SL[4][N4];     // 16 KB cross-group combine buffer
  __shared__ float outl[RPB];
  __shared__ float rf_l[RPB];
  __shared__ float sxAll[T_STEPS];

  const int tid = threadIdx.x;
  const int b = blockIdx.x;
  const int w = tid >> 6;    // wave id == local row (pass1)
  const int l = tid & 63;    // lane
  const int g = tid >> 8;    // row-group (pass2)
  const int c4 = tid & 255;  // float4-column (pass2)
  const int row = b * RPB + w;

  const f32x4* X4 = (const f32x4*)X;
  const f32x4* W4 = (const f32x4*)W;

  // ---- init ----
#pragma unroll
  for (int k = 0; k < 4; ++k) ((f32x4*)P4)[tid + k * NT] = f32x4{0.f, 0.f, 0.f, 0.f};
  if (tid < N4) F4[tid] = f32x4{1.f, 1.f, 1.f, 1.f};

  // sx for every step up front (X is a fixed input)
  for (int tt = w; tt < T_STEPS; tt += 16) {
    float a = 0.f;
#pragma unroll
    for (int k = 0; k < 4; ++k) {
      f32x4 x = X4[tt * N4 + l + 64 * k];
      a += x.x + x.y + x.z + x.w;
    }
    a = wred(a);
    if (l == 0) sxAll[tt] = a;
  }

  // W row fragment in registers
  f32x4 wr[4];
#pragma unroll
  for (int k = 0; k < 4; ++k) wr[k] = W4[(size_t)row * N4 + l + 64 * k];

  // per-parity previous accumulator values (threads tid<N4 own cols 4tid..4tid+3)
  unsigned long long prev[2][4] = {{0ull, 0ull, 0ull, 0ull},
                                   {0ull, 0ull, 0ull, 0ull}};

  __syncthreads();

  for (int t = 0; t < T_STEPS; ++t) {
    // ---- pass 1: out_i and R_i ----
    float a_out = 0.f, a_R = 0.f;
#pragma unroll
    for (int k = 0; k < 4; ++k) {
      const int j4 = l + 64 * k;
      f32x4 p = P4[w][j4];
      f32x4 f = F4[j4];
      f32x4 x = X4[t * N4 + j4];
      f32x4 pf = p * f;
      a_R += pf.x + pf.y + pf.z + pf.w;
      f32x4 s = (pf + wr[k]) * x;
      a_out += s.x + s.y + s.z + s.w;
    }
    float out = wred(a_out);
    float R = wred(a_R);
    if (l == 0) {
      OUT[t * N + row] = out;
      float R1 = R + LMBDA * out * sxAll[t];
      rf_l[w] = (R1 > 1.0f) ? 1.0f / R1 : 1.0f;  // MAX_POST = 1
      outl[w] = LMBDA * out;
    }
    if (t == T_STEPS - 1) break;  // state update past last output is dead work
    __syncthreads();

    // ---- pass 2: apply f, rank-1 update, row renorm (4 rows/thread) ----
    {
      f32x4 fc = F4[c4];
      f32x4 xt = X4[t * N4 + c4];
      f32x4 acc = f32x4{0.f, 0.f, 0.f, 0.f};
#pragma unroll
      for (int r = 0; r < 4; ++r) {
        const int rr = 4 * g + r;
        f32x4 p = P4[rr][c4];
        f32x4 v = rf_l[rr] * (p * fc + outl[rr] * xt);
        P4[rr][c4] = v;
        acc += v;
      }
      SL[g][c4] = acc;
    }
    __syncthreads();

    const int p = t & 1;
    unsigned long long* Sb = Sacc + (size_t)p * N;

    // ---- publish: fixed-point atomic adds (exactly commutative) ----
    if (tid < N4) {
      f32x4 s = SL[0][tid] + SL[1][tid] + SL[2][tid] + SL[3][tid];
#pragma unroll
      for (int k = 0; k < 4; ++k) {
        double sd = (double)s[k] * SCALE_D;
        long long q = (long long)rint(sd);
        __hip_atomic_fetch_add(Sb + 4 * tid + k, (unsigned long long)q,
                               __ATOMIC_RELAXED, __HIP_MEMORY_SCOPE_AGENT);
      }
    }
    __syncthreads();  // all waves' atomics drained (vmcnt) before the flag

    // ---- flag barrier ----
    if (w == 0) {
      const unsigned target = t + 1u;
      if (l == 0)
        __hip_atomic_store(&flags[b], target, __ATOMIC_RELAXED,
                           __HIP_MEMORY_SCOPE_AGENT);
      for (;;) {
        unsigned v = __hip_atomic_load(&flags[l], __ATOMIC_RELAXED,
                                       __HIP_MEMORY_SCOPE_AGENT);
        if (__all(v >= target)) break;
        __builtin_amdgcn_s_sleep(1);
      }
    }
    __syncthreads();

    // ---- consume: read 8 KB, exact integer delta, new column factor ----
    if (tid < N4) {
      unsigned long long cur[4];
#pragma unroll
      for (int k = 0; k < 4; ++k)
        cur[k] = __hip_atomic_load(Sb + 4 * tid + k, __ATOMIC_RELAXED,
                                   __HIP_MEMORY_SCOPE_AGENT);
      f32x4 f;
#pragma unroll
      for (int k = 0; k < 4; ++k) {
        long long d = (long long)(cur[k] - prev[p][k]);
        prev[p][k] = cur[k];
        float sv = (float)((double)d * INV_SCALE_D);
        ((float*)&f)[k] = (sv > 1.0f) ? 1.0f / sv : 1.0f;  // MAX_PRE = 1
      }
      F4[tid] = f;
    }
    __syncthreads();
  }
}

extern "C" void kernel_launch(void* const* d_in, const int* in_sizes, int n_in,
                              void* d_out, int out_size, void* d_ws, size_t ws_size,
                              hipStream_t stream) {
  const float* X = (const float*)d_in[0];   // inputs [128][1024]
  const float* W = (const float*)d_in[2];   // out_in_fixed [1024][1024]
  float* OUT = (float*)d_out;               // [128][1024] f32

  char* ws = (char*)d_ws;
  unsigned long long* Sacc = (unsigned long long*)ws;      // 2*N*8 = 16 KB
  unsigned* flags = (unsigned*)(ws + (size_t)2 * N * 8);   // 256 B

  // Sacc and flags must start at 0 on every launch (ws poisoned 0xAA once;
  // graph replays re-run this memset). One contiguous async memset.
  hipMemsetAsync(ws, 0, (size_t)2 * N * 8 + NB * sizeof(unsigned), stream);

  hipLaunchKernelGGL(rf_step_kernel, dim3(NB), dim3(NT), 0, stream,
                     X, W, OUT, Sacc, flags);
}

// Round 6
// 634.120 us; speedup vs baseline: 1.9012x; 1.9012x over previous
//
#include <hip/hip_runtime.h>

// RFNetwork recurrence (in_in_p dead; P = out_in_p):
//   out_t = (W+P) @ x_t ; P = colrenorm(rowrenorm(P + l*outer(out,x)))
// 2D decomposition: 16x16 grid of blocks, block (r,c) owns a 64x64 tile of
// P_tilde in LDS (one-step-lazy column factor f as before, P_true = Pt * f).
// Per step:
//  1. pass1 partial: tile-local (out,R) partials over its 64 cols
//  2. publish OutP[p][c][64r..] (float2), flagA, pollA(row∪col, radix 31)
//  3. read 16 chunks -> out_i, R_i; r_i = 1/max(R1,1); (c==0 writes OUT)
//  4. pass2: Pt <- r_i*(Pt*f + l*out_i*x) column-wise; tile colsums
//  5. publish Scol[p][r][64c..], flagB, pollB(row∪col)
//  6. read 16 chunks -> colsum s; f = s>1 ? 1/s : 1   (only own 64 cols!)
// Exchange per block per step: ~0.8 KB stored, ~9 KB read (vs 256 KB in 1D).
// Subgroup barriers: flags duplicated row-major+col-major so each poll
// touches 2 cache lines. Monotone flags + parity dbuf; safety:
//   OutP[p] overwrite @t+2 gated by pollB(t+1) over row-mates (their
//   flagsB=t+1 follows their OutP read of step t);
//   Scol[p] overwrite @t+2 gated by pollA(t+2) over col-mates (their
//   flagsA=t+2 follows their Scol read of step t).
// P tile LDS swizzle: f32x4 chunk index ^= (row&15) -> pass1 b128 row reads
// conflict-free-equivalent, pass2 b32 column reads 2-way (free).
// All reduction orders fixed -> bit-deterministic. No data atomics.

typedef float f32x4 __attribute__((ext_vector_type(4)));
typedef float f32x2 __attribute__((ext_vector_type(2)));

#define T_STEPS 128
#define N 1024
#define GR 16
#define GC 16
#define TB 64
#define NT 256
#define LMBDA 0.01f

__global__ __launch_bounds__(NT) void rf2d_kernel(
    const float* __restrict__ X,    // [T][N]
    const float* __restrict__ W,    // [N][N]
    float* __restrict__ OUT,        // [T][N]
    f32x2* __restrict__ OutP,       // [2][GC][N] (out,R) partials
    float* __restrict__ Scol,       // [2][GR][N] colsum partials
    unsigned* __restrict__ fAr, unsigned* __restrict__ fAc,   // [16][16] each
    unsigned* __restrict__ fBr, unsigned* __restrict__ fBc) {
  __shared__ float Pl[TB * TB];     // 16 KB, chunk-swizzled
  __shared__ float f_loc[TB];       // column factor for own 64 cols
  __shared__ float rfl[TB], outll[TB];
  __shared__ float SLc[4][TB];
  __shared__ float sxAll[T_STEPS];

  const int tid = threadIdx.x;
  const int b = blockIdx.x;
  const int r = b >> 4, c = b & 15;
  const int grow = r * TB, gcol = c * TB;

  const int r_loc = tid >> 2, q = tid & 3;   // pass1: 4 lanes per row
  const int c_loc = tid & 63, rg = tid >> 6; // pass2: thread = column slice

  // ---- init ----
  for (int i = tid; i < TB * TB; i += NT) Pl[i] = 0.f;
  if (tid < TB) f_loc[tid] = 1.f;
  if (tid < T_STEPS) {  // sx[t] precompute (X fixed); sequential = deterministic
    const f32x4* X4 = (const f32x4*)(X + (size_t)tid * N);
    float a = 0.f;
    for (int j = 0; j < N / 4; ++j) { f32x4 v = X4[j]; a += v.x + v.y + v.z + v.w; }
    sxAll[tid] = a;
  }
  // W tile registers: rows grow+r_loc, cols gcol+16q+4k
  f32x4 wr[4];
#pragma unroll
  for (int k = 0; k < 4; ++k)
    wr[k] = *(const f32x4*)(W + (size_t)(grow + r_loc) * N + gcol + 16 * q + 4 * k);

  __syncthreads();

  for (int t = 0; t < T_STEPS; ++t) {
    const int p = t & 1;
    const unsigned tg = t + 1u;

    // ---- 1: pass1 tile partial ----
    float a_out = 0.f, a_R = 0.f;
#pragma unroll
    for (int k = 0; k < 4; ++k) {
      const int chunk = q * 4 + k;
      f32x4 pv = ((const f32x4*)Pl)[r_loc * 16 + (chunk ^ (r_loc & 15))];
      f32x4 fv = ((const f32x4*)f_loc)[chunk];
      f32x4 xv = *(const f32x4*)(X + (size_t)t * N + gcol + 16 * q + 4 * k);
      f32x4 pf = pv * fv;
      a_R += pf.x + pf.y + pf.z + pf.w;
      f32x4 s = (pf + wr[k]) * xv;
      a_out += s.x + s.y + s.z + s.w;
    }
    a_out += __shfl_xor(a_out, 1, 64); a_out += __shfl_xor(a_out, 2, 64);
    a_R   += __shfl_xor(a_R, 1, 64);   a_R   += __shfl_xor(a_R, 2, 64);

    // ---- 2: publish (out,R) partial; flagA; pollA over row∪col ----
    if (q == 0) {
      f32x2 v; v.x = a_out; v.y = a_R;
      f32x2* dst = OutP + ((size_t)p * GC + c) * N + grow + r_loc;
      asm volatile("global_store_dwordx2 %0, %1, off sc0 sc1"
                   :: "v"(dst), "v"(v) : "memory");
    }
    __syncthreads();  // per-wave vmcnt drained -> partials at LLC
    if (tid == 0) {
      __hip_atomic_store(&fAr[r * GC + c], tg, __ATOMIC_RELAXED, __HIP_MEMORY_SCOPE_AGENT);
      __hip_atomic_store(&fAc[c * GR + r], tg, __ATOMIC_RELAXED, __HIP_MEMORY_SCOPE_AGENT);
    }
    if (tid < 32) {
      const unsigned* pp = (tid < 16) ? &fAr[r * GC + tid] : &fAc[c * GR + (tid - 16)];
      while (__hip_atomic_load(pp, __ATOMIC_RELAXED, __HIP_MEMORY_SCOPE_AGENT) < tg)
        __builtin_amdgcn_s_sleep(1);
    }
    __syncthreads();

    // ---- 3: reduce 16 chunks -> out_i, R_i ----
    {
      const f32x2* base = OutP + (size_t)p * GC * N + grow + r_loc;
      f32x2 vv[4];
#pragma unroll
      for (int i = 0; i < 4; ++i) {
        const f32x2* ap = base + (size_t)(4 * q + i) * N;
        asm volatile("global_load_dwordx2 %0, %1, off sc0 sc1"
                     : "=v"(vv[i]) : "v"(ap) : "memory");
      }
      asm volatile("s_waitcnt vmcnt(0)" ::: "memory");
      __builtin_amdgcn_sched_barrier(0);
      f32x2 s2 = (vv[0] + vv[1]) + (vv[2] + vv[3]);
      s2.x += __shfl_xor(s2.x, 1, 64); s2.x += __shfl_xor(s2.x, 2, 64);
      s2.y += __shfl_xor(s2.y, 1, 64); s2.y += __shfl_xor(s2.y, 2, 64);
      float out = s2.x;
      float ol = LMBDA * out;
      float R1 = s2.y + ol * sxAll[t];
      float rf = (R1 > 1.f) ? 1.f / R1 : 1.f;  // MAX_POST = 1
      if (q == 0) { rfl[r_loc] = rf; outll[r_loc] = ol; }
      if (c == 0 && q == 0) OUT[(size_t)t * N + grow + r_loc] = out;
    }
    if (t == T_STEPS - 1) break;  // state update past last output is dead work
    __syncthreads();

    // ---- 4: pass2 column-wise update + tile colsums ----
    {
      const float xc = X[(size_t)t * N + gcol + c_loc];
      const float fc = f_loc[c_loc];
      float cacc = 0.f;
#pragma unroll
      for (int rr = 0; rr < 16; ++rr) {
        const int row = rg * 16 + rr;
        const int idx = row * 64 + ((((c_loc >> 2) ^ (row & 15))) << 2) + (c_loc & 3);
        float v = rfl[row] * (Pl[idx] * fc + outll[row] * xc);
        Pl[idx] = v;
        cacc += v;
      }
      SLc[rg][c_loc] = cacc;
    }
    __syncthreads();

    // ---- 5: publish colsum partial; flagB; pollB over row∪col ----
    if (tid < TB) {
      float scol = (SLc[0][tid] + SLc[1][tid]) + (SLc[2][tid] + SLc[3][tid]);
      float* dst = Scol + ((size_t)p * GR + r) * N + gcol + tid;
      asm volatile("global_store_dword %0, %1, off sc0 sc1"
                   :: "v"(dst), "v"(scol) : "memory");
    }
    __syncthreads();
    if (tid == 0) {
      __hip_atomic_store(&fBr[r * GC + c], tg, __ATOMIC_RELAXED, __HIP_MEMORY_SCOPE_AGENT);
      __hip_atomic_store(&fBc[c * GR + r], tg, __ATOMIC_RELAXED, __HIP_MEMORY_SCOPE_AGENT);
    }
    if (tid < 32) {
      const unsigned* pp = (tid < 16) ? &fBr[r * GC + tid] : &fBc[c * GR + (tid - 16)];
      while (__hip_atomic_load(pp, __ATOMIC_RELAXED, __HIP_MEMORY_SCOPE_AGENT) < tg)
        __builtin_amdgcn_s_sleep(1);
    }
    __syncthreads();

    // ---- 6: reduce 16 colsum chunks (own 64 cols) -> f ----
    {
      const float* base = Scol + (size_t)p * GR * N + gcol + c_loc;
      float vv[4];
#pragma unroll
      for (int i = 0; i < 4; ++i) {
        const float* ap = base + (size_t)(4 * rg + i) * N;
        asm volatile("global_load_dword %0, %1, off sc0 sc1"
                     : "=v"(vv[i]) : "v"(ap) : "memory");
      }
      asm volatile("s_waitcnt vmcnt(0)" ::: "memory");
      __builtin_amdgcn_sched_barrier(0);
      SLc[rg][c_loc] = (vv[0] + vv[1]) + (vv[2] + vv[3]);
    }
    __syncthreads();
    if (tid < TB) {
      float s = (SLc[0][tid] + SLc[1][tid]) + (SLc[2][tid] + SLc[3][tid]);
      f_loc[tid] = (s > 1.f) ? 1.f / s : 1.f;  // MAX_PRE = 1
    }
    __syncthreads();
  }
}

extern "C" void kernel_launch(void* const* d_in, const int* in_sizes, int n_in,
                              void* d_out, int out_size, void* d_ws, size_t ws_size,
                              hipStream_t stream) {
  const float* X = (const float*)d_in[0];   // inputs [128][1024]
  const float* W = (const float*)d_in[2];   // out_in_fixed [1024][1024]
  float* OUT = (float*)d_out;               // [128][1024] f32

  char* ws = (char*)d_ws;
  // layout: flags (4 KB, memset 0) | OutP (256 KB) | Scol (128 KB)
  unsigned* fAr = (unsigned*)ws;
  unsigned* fAc = fAr + 256;
  unsigned* fBr = fAc + 256;
  unsigned* fBc = fBr + 256;
  f32x2* OutP = (f32x2*)(ws + 4096);
  float* Scol = (float*)(ws + 4096 + (size_t)2 * GC * N * 8);

  // flags must be zero at every (graph-replayed) launch; monotone within one
  hipMemsetAsync(ws, 0, 4096, stream);

  hipLaunchKernelGGL(rf2d_kernel, dim3(GR * GC), dim3(NT), 0, stream,
                     X, W, OUT, OutP, Scol, fAr, fAc, fBr, fBc);
}